// Round 7
// baseline (339.083 us; speedup 1.0000x reference)
//
#include <hip/hip_runtime.h>

// ---------------- problem constants ----------------
#define N_NODES 10000
#define IN_DIM  512
#define OUT_DIM 128
#define NE      262144
#define K_DIM   10000
#define HT_S    10048          // padded hT stride (zeros in [10000,10048))

// ---------------- GEMM2 (adj @ h) tiling ----------------
#define BM 128
#define BN 128
#define BK 64
#define SPLITS 16
#define KSTEPS_TOTAL 157       // ceil(10000/64)
#define STEPS_PER_SPLIT 10     // 15*10 + 7 = 157
#define ADJ_REPEAT 3           // DIAGNOSTIC: repeat K-loop so k_adj's dispatch
                               // outlasts the harness fills and shows up in the
                               // rocprof top-5 with real counters. Revert to 1.

typedef __attribute__((ext_vector_type(8))) __bf16 bf16x8;
typedef __attribute__((ext_vector_type(4))) float  f32x4;

__device__ inline ushort f2bf(float f) {
    uint u = __float_as_uint(f);
    return (ushort)((u + 0x7fffu + ((u >> 16) & 1u)) >> 16);
}
__device__ inline float bf2f(ushort s) {
    return __uint_as_float(((uint)s) << 16);
}

// async global -> LDS, 16 bytes per lane (global_load_lds_dwordx4)
__device__ __forceinline__ void gl2lds16(const void* g, void* l) {
    __builtin_amdgcn_global_load_lds(
        (const __attribute__((address_space(1))) void*)g,
        (__attribute__((address_space(3))) void*)l, 16, 0, 0);
}

// ---------------- kernel 0: WT = W^T bf16, v = W2 @ w3[:128], hT pad zero ----
__global__ __launch_bounds__(256) void k_prep(const float* __restrict__ w,
                                              const float* __restrict__ w2,
                                              const float* __restrict__ w3,
                                              ushort* __restrict__ WT,
                                              float* __restrict__ v,
                                              ushort* __restrict__ hT) {
    const int t = threadIdx.x;
    for (int idx = blockIdx.x * 256 + t; idx < IN_DIM * OUT_DIM; idx += gridDim.x * 256) {
        int k = idx >> 7, n = idx & 127;
        WT[n * IN_DIM + k] = f2bf(w[idx]);
    }
    if (blockIdx.x == 0) {
        float s = 0.f;
        for (int j = 0; j < OUT_DIM; ++j) s += w2[t * OUT_DIM + j] * w3[j];
        v[t] = s;
    }
    if (blockIdx.x == 1) {
        for (int idx = t; idx < 128 * (HT_S - N_NODES); idx += 256) {
            int c = idx / (HT_S - N_NODES), r = idx % (HT_S - N_NODES);
            hT[(size_t)c * HT_S + N_NODES + r] = 0;
        }
    }
}

// ---------------- kernel 1: hT[c][r] = (x @ W)[r][c] bf16, MFMA ----------------
__global__ __launch_bounds__(128) void k_xw(const float* __restrict__ x,
                                            const ushort* __restrict__ WT,
                                            ushort* __restrict__ hT) {
    const int tid = threadIdx.x, wave = tid >> 6, lane = tid & 63;
    const int lr = lane & 15, lg = lane >> 4;
    const int arow = blockIdx.x * 32 + wave * 16 + lr;
    const bool aok = arow < N_NODES;
    const float* pA = x + (size_t)arow * IN_DIM;

    f32x4 acc[8];
#pragma unroll
    for (int nf = 0; nf < 8; ++nf) acc[nf] = (f32x4){0.f, 0.f, 0.f, 0.f};

#pragma unroll 2
    for (int st = 0; st < 8; ++st) {
        const int k0 = st * 64;
        bf16x8 abf[2];
#pragma unroll
        for (int kh = 0; kh < 2; ++kh) {
            float4 a0 = make_float4(0.f, 0.f, 0.f, 0.f), a1 = a0;
            if (aok) {
                a0 = *(const float4*)(pA + k0 + kh * 32 + lg * 8);
                a1 = *(const float4*)(pA + k0 + kh * 32 + lg * 8 + 4);
            }
            ushort* ap = (ushort*)&abf[kh];
            ap[0] = f2bf(a0.x); ap[1] = f2bf(a0.y); ap[2] = f2bf(a0.z); ap[3] = f2bf(a0.w);
            ap[4] = f2bf(a1.x); ap[5] = f2bf(a1.y); ap[6] = f2bf(a1.z); ap[7] = f2bf(a1.w);
        }
#pragma unroll
        for (int kh = 0; kh < 2; ++kh)
#pragma unroll
            for (int nf = 0; nf < 8; ++nf) {
                bf16x8 bfv = *(const bf16x8*)(WT + (size_t)(nf * 16 + lr) * IN_DIM + k0 + kh * 32 + lg * 8);
                acc[nf] = __builtin_amdgcn_mfma_f32_16x16x32_bf16(abf[kh], bfv, acc[nf], 0, 0, 0);
            }
    }

    const int m0 = blockIdx.x * 32 + wave * 16 + lg * 4;
    if (m0 < N_NODES) {
#pragma unroll
        for (int nf = 0; nf < 8; ++nf) {
            int c = nf * 16 + lr;
            ushort4 pk;
            pk.x = f2bf(acc[nf][0]); pk.y = f2bf(acc[nf][1]);
            pk.z = f2bf(acc[nf][2]); pk.w = f2bf(acc[nf][3]);
            *(ushort4*)(hT + (size_t)c * HT_S + m0) = pk;
        }
    }
}

// ---------------- kernel 2: zp[split] = adj @ h, BM=128 single-buffer --------
// DIAGNOSTIC build: K-loop repeated ADJ_REPEAT times (acc re-zeroed each rep,
// same result written once). gl2lds + barriers have side effects -> reps are
// not DCE'd. Counters for this dispatch = steady-state k_adj behavior.
__global__ __launch_bounds__(256) void k_adj(const float* __restrict__ adj,
                                             const ushort* __restrict__ hT,
                                             float* __restrict__ zp) {
    __shared__ float  As[BM * BK];        // 32 KB
    __shared__ ushort Bs[BN * BK];        // 16 KB

    const int tid = threadIdx.x, wave = tid >> 6, lane = tid & 63;
    const int lr = lane & 15, lg = lane >> 4;
    const int m0 = blockIdx.x * BM;
    const int split = blockIdx.y;
    const int step0 = split * STEPS_PER_SPLIT;
    const int step1 = min(step0 + STEPS_PER_SPLIT, KSTEPS_TOTAL);

    // --- per-thread staging descriptors (loop-invariant) ---
    long  abase[8];
    char* aldst[8];
#pragma unroll
    for (int q = 0; q < 8; ++q) {
        int c = tid + q * 256;
        int row = c >> 4, ch = c & 15;
        int grow = m0 + row; if (grow > N_NODES - 1) grow = N_NODES - 1;
        abase[q] = (long)grow * K_DIM + (long)((ch ^ (row & 7)) * 4);
        aldst[q] = (char*)As + c * 16;
    }
    long  bbase[4];
    char* bldst[4];
#pragma unroll
    for (int q = 0; q < 4; ++q) {
        int c = tid + q * 256;
        int row = c >> 3, ch = c & 7;
        bbase[q] = (long)row * HT_S + (long)((ch ^ (row & 7)) * 8);
        bldst[q] = (char*)Bs + c * 16;
    }
    const long ALIMIT = (long)K_DIM * N_NODES - 4;

    f32x4 acc[2][8];

    const int  arow0 = wave * 32 + lr;          // mf=0 row; mf=1 is +16 (same &7)
    const int  asw   = (arow0 & 7) << 4;
    const char* Ab = (const char*)As;
    const char* Bb = (const char*)Bs;

#pragma unroll 1
    for (int rep = 0; rep < ADJ_REPEAT; ++rep) {
#pragma unroll
        for (int mf = 0; mf < 2; ++mf)
#pragma unroll
            for (int nf = 0; nf < 8; ++nf) acc[mf][nf] = (f32x4){0.f, 0.f, 0.f, 0.f};

        for (int st = step0; st < step1; ++st) {
            const int k0 = st * BK;

            // stage A (HBM) then B (L2/L3) — async DMA, 12 ops/thread
#pragma unroll
            for (int q = 0; q < 8; ++q) {
                long off = abase[q] + k0;
                if (off > ALIMIT) off = ALIMIT;
                gl2lds16(adj + off, aldst[q]);
            }
#pragma unroll
            for (int q = 0; q < 4; ++q)
                gl2lds16(hT + (bbase[q] + k0), bldst[q]);

            __syncthreads();   // vmcnt(0) drain + barrier: tiles ready

#pragma unroll
            for (int kh = 0; kh < 2; ++kh) {
                const int o0 = kh * 128 + lg * 32;
                bf16x8 abf[2];
#pragma unroll
                for (int mf = 0; mf < 2; ++mf) {
                    const int abyte = (arow0 + mf * 16) * 256;
                    float4 fa0 = *(const float4*)(Ab + abyte + ((o0)      ^ asw));
                    float4 fa1 = *(const float4*)(Ab + abyte + ((o0 + 16) ^ asw));
                    ushort* ap = (ushort*)&abf[mf];
                    ap[0] = f2bf(fa0.x); ap[1] = f2bf(fa0.y); ap[2] = f2bf(fa0.z); ap[3] = f2bf(fa0.w);
                    ap[4] = f2bf(fa1.x); ap[5] = f2bf(fa1.y); ap[6] = f2bf(fa1.z); ap[7] = f2bf(fa1.w);
                }
#pragma unroll
                for (int nf = 0; nf < 8; ++nf) {
                    int brow = nf * 16 + lr;
                    bf16x8 bv = *(const bf16x8*)(Bb + brow * 128 + ((kh * 64 + lg * 16) ^ ((brow & 7) << 4)));
                    acc[0][nf] = __builtin_amdgcn_mfma_f32_16x16x32_bf16(abf[0], bv, acc[0][nf], 0, 0, 0);
                    acc[1][nf] = __builtin_amdgcn_mfma_f32_16x16x32_bf16(abf[1], bv, acc[1][nf], 0, 0, 0);
                }
            }

            __syncthreads();   // protect LDS before next-step overwrite
        }
    }

    // epilogue: write split-partial z (result of the last rep == every rep)
    float* out = zp + (size_t)split * N_NODES * OUT_DIM;
#pragma unroll
    for (int mf = 0; mf < 2; ++mf) {
        const int orow = m0 + wave * 32 + mf * 16 + lg * 4;
#pragma unroll
        for (int nf = 0; nf < 8; ++nf)
#pragma unroll
            for (int r = 0; r < 4; ++r) {
                int row = orow + r;
                if (row < N_NODES)
                    out[(size_t)row * OUT_DIM + nf * 16 + lr] = acc[mf][nf][r];
            }
    }
}

// ---------------- kernel 3: reduce splits + per-node precompute (bf16 out) ---
__global__ __launch_bounds__(256) void k_node(const float* __restrict__ zp,
                                              const float* __restrict__ v,
                                              const float* __restrict__ w3,
                                              float* __restrict__ a,
                                              float* __restrict__ b,
                                              ushort* __restrict__ zb,
                                              ushort* __restrict__ zwb) {
    const int wave = threadIdx.x >> 6, lane = threadIdx.x & 63;
    const int i = blockIdx.x * 4 + wave;
    if (i >= N_NODES) return;
    const int k0 = lane, k1 = lane + 64;

    float z0 = 0.f, z1 = 0.f;
#pragma unroll
    for (int s = 0; s < SPLITS; ++s) {
        const float* row = zp + ((size_t)s * N_NODES + i) * OUT_DIM;
        z0 += row[k0];
        z1 += row[k1];
    }
    zb[(size_t)i * OUT_DIM + k0]  = f2bf(z0);
    zb[(size_t)i * OUT_DIM + k1]  = f2bf(z1);
    zwb[(size_t)i * OUT_DIM + k0] = f2bf(z0 * w3[OUT_DIM + k0]);
    zwb[(size_t)i * OUT_DIM + k1] = f2bf(z1 * w3[OUT_DIM + k1]);

    float ra = fmaxf(z0, 0.f) * v[k0] + fmaxf(z1, 0.f) * v[k1];
    float rb = fmaxf(z0, 0.f) * v[OUT_DIM + k0] + fmaxf(z1, 0.f) * v[OUT_DIM + k1];
#pragma unroll
    for (int off = 32; off; off >>= 1) {
        ra += __shfl_down(ra, off);
        rb += __shfl_down(rb, off);
    }
    if (lane == 0) { a[i] = ra; b[i] = rb; }
}

// ---------------- kernel 4: per-edge logit + sigmoid (2 edges / wave) --------
__global__ __launch_bounds__(256) void k_edge(const int* __restrict__ e_true,
                                              const int* __restrict__ e_false,
                                              const float* __restrict__ a,
                                              const float* __restrict__ b,
                                              const ushort* __restrict__ zb,
                                              const ushort* __restrict__ zwb,
                                              float* __restrict__ out) {
    const int lane = threadIdx.x & 63;
    const int half = lane >> 5, l32 = lane & 31;
    const int gw   = (blockIdx.x * blockDim.x + threadIdx.x) >> 6;
    const int nw   = (gridDim.x * blockDim.x) >> 6;

    for (int e = gw * 2 + half; e < 2 * NE; e += nw * 2) {
        int2 ij = (e < NE) ? ((const int2*)e_true)[e] : ((const int2*)e_false)[e - NE];
        int i = ij.x, j = ij.y;

        uint2 zwi = *(const uint2*)(zwb + (size_t)i * OUT_DIM + l32 * 4);
        uint2 zjv = *(const uint2*)(zb  + (size_t)j * OUT_DIM + l32 * 4);
        float d = bf2f((ushort)(zwi.x & 0xffffu)) * bf2f((ushort)(zjv.x & 0xffffu))
                + bf2f((ushort)(zwi.x >> 16))     * bf2f((ushort)(zjv.x >> 16))
                + bf2f((ushort)(zwi.y & 0xffffu)) * bf2f((ushort)(zjv.y & 0xffffu))
                + bf2f((ushort)(zwi.y >> 16))     * bf2f((ushort)(zjv.y >> 16));
#pragma unroll
        for (int off = 16; off; off >>= 1) d += __shfl_xor(d, off, 32);
        if (l32 == 0) {
            float logit = a[i] + b[j] + d;
            out[e] = 1.0f / (1.0f + __expf(-logit));
        }
    }
}

// ---------------- launch ----------------
extern "C" void kernel_launch(void* const* d_in, const int* in_sizes, int n_in,
                              void* d_out, int out_size, void* d_ws, size_t ws_size,
                              hipStream_t stream) {
    const float* x      = (const float*)d_in[0];
    const float* adj    = (const float*)d_in[1];
    const float* w      = (const float*)d_in[2];
    const float* w2     = (const float*)d_in[3];
    const float* w3     = (const float*)d_in[4];
    const int* e_true   = (const int*)d_in[5];
    const int* e_false  = (const int*)d_in[6];
    float* out          = (float*)d_out;

    char* ws = (char*)d_ws;
    // workspace layout (bytes)
    ushort* hT  = (ushort*)(ws);                        //  2,572,288 (128 x 10048 bf16)
    float*  zp  = (float*)(ws + 2572288);               // 81,920,000 (16 x 10000 x 128 f32)
    float*  v   = (float*)(ws + 84492288);              //      1,024
    float*  a   = (float*)(ws + 84493312);              //     40,000
    float*  b   = (float*)(ws + 84533312);              //     40,000
    ushort* zb  = (ushort*)(ws + 84573312);             //  2,560,000
    ushort* zwb = (ushort*)(ws + 87133312);             //  2,560,000
    ushort* WT  = (ushort*)(ws + 89693312);             //    131,072  -> ~89.8 MB

    k_prep<<<64, 256, 0, stream>>>(w, w2, w3, WT, v, hT);
    k_xw<<<313, 128, 0, stream>>>(x, WT, hT);
    k_adj<<<dim3(79, SPLITS), 256, 0, stream>>>(adj, hT, zp);
    k_node<<<2500, 256, 0, stream>>>(zp, v, w3, a, b, zb, zwb);
    k_edge<<<2048, 256, 0, stream>>>(e_true, e_false, a, b, zb, zwb, out);
}

// Round 8
// 208.778 us; speedup vs baseline: 1.6241x; 1.6241x over previous
//
#include <hip/hip_runtime.h>

// ---------------- problem constants ----------------
#define N_NODES 10000
#define IN_DIM  512
#define OUT_DIM 128
#define NE      262144
#define K_DIM   10000
#define HT_S    10048          // padded hT stride (zeros in [10000,10048))

// ---------------- GEMM2 (adj @ h) tiling ----------------
#define BM 128
#define BN 128
#define BK 64
#define SPLITS 8
#define KSTEPS_TOTAL 157       // ceil(10000/64)
#define STEPS_PER_SPLIT 20     // 7*20 + 17 = 157

typedef __attribute__((ext_vector_type(8))) __bf16 bf16x8;
typedef __attribute__((ext_vector_type(4))) float  f32x4;

__device__ inline ushort f2bf(float f) {
    uint u = __float_as_uint(f);
    return (ushort)((u + 0x7fffu + ((u >> 16) & 1u)) >> 16);
}
__device__ inline float bf2f(ushort s) {
    return __uint_as_float(((uint)s) << 16);
}

// async global -> LDS, 16 bytes per lane (global_load_lds_dwordx4)
__device__ __forceinline__ void gl2lds16(const void* g, void* l) {
    __builtin_amdgcn_global_load_lds(
        (const __attribute__((address_space(1))) void*)g,
        (__attribute__((address_space(3))) void*)l, 16, 0, 0);
}

// ---------------- kernel 0: WT = W^T bf16, v = W2 @ w3[:128], hT pad zero ----
__global__ __launch_bounds__(256) void k_prep(const float* __restrict__ w,
                                              const float* __restrict__ w2,
                                              const float* __restrict__ w3,
                                              ushort* __restrict__ WT,
                                              float* __restrict__ v,
                                              ushort* __restrict__ hT) {
    const int t = threadIdx.x;
    for (int idx = blockIdx.x * 256 + t; idx < IN_DIM * OUT_DIM; idx += gridDim.x * 256) {
        int k = idx >> 7, n = idx & 127;
        WT[n * IN_DIM + k] = f2bf(w[idx]);
    }
    if (blockIdx.x == 0) {
        float s = 0.f;
        for (int j = 0; j < OUT_DIM; ++j) s += w2[t * OUT_DIM + j] * w3[j];
        v[t] = s;
    }
    if (blockIdx.x == 1) {
        for (int idx = t; idx < 128 * (HT_S - N_NODES); idx += 256) {
            int c = idx / (HT_S - N_NODES), r = idx % (HT_S - N_NODES);
            hT[(size_t)c * HT_S + N_NODES + r] = 0;
        }
    }
}

// ---------------- kernel 1: hT = (x @ W)^T bf16. One wave per 16x32 tile -----
// 625 x 4 grid of 64-thread blocks = 2500 waves (was 626 -> latency-bound).
__global__ __launch_bounds__(64) void k_xw(const float* __restrict__ x,
                                           const ushort* __restrict__ WT,
                                           ushort* __restrict__ hT) {
    const int lane = threadIdx.x;
    const int lr = lane & 15, lg = lane >> 4;
    const int r0 = blockIdx.x * 16;       // 625 * 16 = 10000 exactly
    const int c0 = blockIdx.y * 32;       // 4 col-groups
    const float* pA = x + (size_t)(r0 + lr) * IN_DIM;

    f32x4 acc[2];
#pragma unroll
    for (int nf = 0; nf < 2; ++nf) acc[nf] = (f32x4){0.f, 0.f, 0.f, 0.f};

#pragma unroll
    for (int st = 0; st < 8; ++st) {
        const int k0 = st * 64;
        bf16x8 abf[2];
#pragma unroll
        for (int kh = 0; kh < 2; ++kh) {
            float4 a0 = *(const float4*)(pA + k0 + kh * 32 + lg * 8);
            float4 a1 = *(const float4*)(pA + k0 + kh * 32 + lg * 8 + 4);
            ushort* ap = (ushort*)&abf[kh];
            ap[0] = f2bf(a0.x); ap[1] = f2bf(a0.y); ap[2] = f2bf(a0.z); ap[3] = f2bf(a0.w);
            ap[4] = f2bf(a1.x); ap[5] = f2bf(a1.y); ap[6] = f2bf(a1.z); ap[7] = f2bf(a1.w);
        }
#pragma unroll
        for (int kh = 0; kh < 2; ++kh)
#pragma unroll
            for (int nf = 0; nf < 2; ++nf) {
                bf16x8 bfv = *(const bf16x8*)(WT + (size_t)(c0 + nf * 16 + lr) * IN_DIM + k0 + kh * 32 + lg * 8);
                acc[nf] = __builtin_amdgcn_mfma_f32_16x16x32_bf16(abf[kh], bfv, acc[nf], 0, 0, 0);
            }
    }

    const int m0 = r0 + lg * 4;           // rows m0..m0+3, 4-aligned, < 10000
#pragma unroll
    for (int nf = 0; nf < 2; ++nf) {
        int c = c0 + nf * 16 + lr;
        ushort4 pk;
        pk.x = f2bf(acc[nf][0]); pk.y = f2bf(acc[nf][1]);
        pk.z = f2bf(acc[nf][2]); pk.w = f2bf(acc[nf][3]);
        *(ushort4*)(hT + (size_t)c * HT_S + m0) = pk;
    }
}

// ---------------- kernel 2: zp[split] = adj @ h ----------------
// A (adj f32, HBM): DIRECT global->register, 8 dwordx4/thread/step, 32B
// contiguous per lane, converted f2bf in-reg. No LDS for A.
// B (hT bf16, L2): gl2lds staged, single 16 KB buffer, both-sides XOR swizzle.
// Rationale (R7 counters): L3-warm replay ran at identical speed -> per-CU
// consumption cap in the 48KB/step gl2lds+drain path, not memory supply.
__global__ __launch_bounds__(256, 3) void k_adj(const float* __restrict__ adj,
                                                const ushort* __restrict__ hT,
                                                float* __restrict__ zp) {
    __shared__ ushort Bs[BN * BK];        // 16 KB only

    const int tid = threadIdx.x, wave = tid >> 6, lane = tid & 63;
    const int lr = lane & 15, lg = lane >> 4;
    const int m0 = blockIdx.x * BM;
    const int split = blockIdx.y;
    const int step0 = split * STEPS_PER_SPLIT;
    const int step1 = min(step0 + STEPS_PER_SPLIT, KSTEPS_TOTAL);

    // B staging descriptors (loop-invariant)
    long  bbase[4];
    char* bldst[4];
#pragma unroll
    for (int q = 0; q < 4; ++q) {
        int c = tid + q * 256;
        int row = c >> 3, ch = c & 7;
        bbase[q] = (long)row * HT_S + (long)((ch ^ (row & 7)) * 8);
        bldst[q] = (char*)Bs + c * 16;
    }

    // A row pointers (clamped; out-of-range rows' outputs are discarded)
    const int ar0 = min(m0 + wave * 32 + lr,      N_NODES - 1);
    const int ar1 = min(m0 + wave * 32 + 16 + lr, N_NODES - 1);
    const float* pA0 = adj + (size_t)ar0 * K_DIM;
    const float* pA1 = adj + (size_t)ar1 * K_DIM;

    f32x4 acc[2][8];
#pragma unroll
    for (int mf = 0; mf < 2; ++mf)
#pragma unroll
        for (int nf = 0; nf < 8; ++nf) acc[mf][nf] = (f32x4){0.f, 0.f, 0.f, 0.f};

    const char* Bb = (const char*)Bs;

    for (int st = step0; st < step1; ++st) {
        const int k0 = st * BK;

        // stage B via async DMA (16 KB / block / step)
#pragma unroll
        for (int q = 0; q < 4; ++q)
            gl2lds16(hT + (bbase[q] + k0), bldst[q]);

        // A direct to registers: 8 independent dwordx4 (addresses clamped so
        // k-overrun lanes read in-bounds; their products hit B=0 pad rows)
        float4 fa[2][2][2];
#pragma unroll
        for (int kh = 0; kh < 2; ++kh) {
            int kk = k0 + kh * 32 + lg * 8;
            int kc = (kk <= K_DIM - 8) ? kk : (K_DIM - 8);
            fa[0][kh][0] = *(const float4*)(pA0 + kc);
            fa[0][kh][1] = *(const float4*)(pA0 + kc + 4);
            fa[1][kh][0] = *(const float4*)(pA1 + kc);
            fa[1][kh][1] = *(const float4*)(pA1 + kc + 4);
        }

        __syncthreads();   // B tile visible (vmcnt0 also covers A regs)

        bf16x8 abf[2][2];
#pragma unroll
        for (int mf = 0; mf < 2; ++mf)
#pragma unroll
            for (int kh = 0; kh < 2; ++kh) {
                ushort* ap = (ushort*)&abf[mf][kh];
                const float* f0 = (const float*)&fa[mf][kh][0];
#pragma unroll
                for (int e = 0; e < 8; ++e) ap[e] = f2bf(f0[e]);
            }

#pragma unroll
        for (int kh = 0; kh < 2; ++kh)
#pragma unroll
            for (int nf = 0; nf < 8; ++nf) {
                int brow = nf * 16 + lr;
                bf16x8 bv = *(const bf16x8*)(Bb + brow * 128 + ((kh * 64 + lg * 16) ^ ((brow & 7) << 4)));
                acc[0][nf] = __builtin_amdgcn_mfma_f32_16x16x32_bf16(abf[0][kh], bv, acc[0][nf], 0, 0, 0);
                acc[1][nf] = __builtin_amdgcn_mfma_f32_16x16x32_bf16(abf[1][kh], bv, acc[1][nf], 0, 0, 0);
            }

        __syncthreads();   // all B reads done before next-step overwrite
    }

    // epilogue: write split-partial z
    float* out = zp + (size_t)split * N_NODES * OUT_DIM;
#pragma unroll
    for (int mf = 0; mf < 2; ++mf) {
        const int orow = m0 + wave * 32 + mf * 16 + lg * 4;
#pragma unroll
        for (int nf = 0; nf < 8; ++nf)
#pragma unroll
            for (int r = 0; r < 4; ++r) {
                int row = orow + r;
                if (row < N_NODES)
                    out[(size_t)row * OUT_DIM + nf * 16 + lr] = acc[mf][nf][r];
            }
    }
}

// ---------------- kernel 3: reduce splits + per-node precompute (bf16 out) ---
__global__ __launch_bounds__(256) void k_node(const float* __restrict__ zp,
                                              const float* __restrict__ v,
                                              const float* __restrict__ w3,
                                              float* __restrict__ a,
                                              float* __restrict__ b,
                                              ushort* __restrict__ zb,
                                              ushort* __restrict__ zwb) {
    const int wave = threadIdx.x >> 6, lane = threadIdx.x & 63;
    const int i = blockIdx.x * 4 + wave;
    if (i >= N_NODES) return;
    const int k0 = lane, k1 = lane + 64;

    float z0 = 0.f, z1 = 0.f;
#pragma unroll
    for (int s = 0; s < SPLITS; ++s) {
        const float* row = zp + ((size_t)s * N_NODES + i) * OUT_DIM;
        z0 += row[k0];
        z1 += row[k1];
    }
    zb[(size_t)i * OUT_DIM + k0]  = f2bf(z0);
    zb[(size_t)i * OUT_DIM + k1]  = f2bf(z1);
    zwb[(size_t)i * OUT_DIM + k0] = f2bf(z0 * w3[OUT_DIM + k0]);
    zwb[(size_t)i * OUT_DIM + k1] = f2bf(z1 * w3[OUT_DIM + k1]);

    float ra = fmaxf(z0, 0.f) * v[k0] + fmaxf(z1, 0.f) * v[k1];
    float rb = fmaxf(z0, 0.f) * v[OUT_DIM + k0] + fmaxf(z1, 0.f) * v[OUT_DIM + k1];
#pragma unroll
    for (int off = 32; off; off >>= 1) {
        ra += __shfl_down(ra, off);
        rb += __shfl_down(rb, off);
    }
    if (lane == 0) { a[i] = ra; b[i] = rb; }
}

// ---------------- kernel 4: per-edge logit + sigmoid (2 edges / wave) --------
__global__ __launch_bounds__(256) void k_edge(const int* __restrict__ e_true,
                                              const int* __restrict__ e_false,
                                              const float* __restrict__ a,
                                              const float* __restrict__ b,
                                              const ushort* __restrict__ zb,
                                              const ushort* __restrict__ zwb,
                                              float* __restrict__ out) {
    const int lane = threadIdx.x & 63;
    const int half = lane >> 5, l32 = lane & 31;
    const int gw   = (blockIdx.x * blockDim.x + threadIdx.x) >> 6;
    const int nw   = (gridDim.x * blockDim.x) >> 6;

    for (int e = gw * 2 + half; e < 2 * NE; e += nw * 2) {
        int2 ij = (e < NE) ? ((const int2*)e_true)[e] : ((const int2*)e_false)[e - NE];
        int i = ij.x, j = ij.y;

        uint2 zwi = *(const uint2*)(zwb + (size_t)i * OUT_DIM + l32 * 4);
        uint2 zjv = *(const uint2*)(zb  + (size_t)j * OUT_DIM + l32 * 4);
        float d = bf2f((ushort)(zwi.x & 0xffffu)) * bf2f((ushort)(zjv.x & 0xffffu))
                + bf2f((ushort)(zwi.x >> 16))     * bf2f((ushort)(zjv.x >> 16))
                + bf2f((ushort)(zwi.y & 0xffffu)) * bf2f((ushort)(zjv.y & 0xffffu))
                + bf2f((ushort)(zwi.y >> 16))     * bf2f((ushort)(zjv.y >> 16));
#pragma unroll
        for (int off = 16; off; off >>= 1) d += __shfl_xor(d, off, 32);
        if (l32 == 0) {
            float logit = a[i] + b[j] + d;
            out[e] = 1.0f / (1.0f + __expf(-logit));
        }
    }
}

// ---------------- launch ----------------
extern "C" void kernel_launch(void* const* d_in, const int* in_sizes, int n_in,
                              void* d_out, int out_size, void* d_ws, size_t ws_size,
                              hipStream_t stream) {
    const float* x      = (const float*)d_in[0];
    const float* adj    = (const float*)d_in[1];
    const float* w      = (const float*)d_in[2];
    const float* w2     = (const float*)d_in[3];
    const float* w3     = (const float*)d_in[4];
    const int* e_true   = (const int*)d_in[5];
    const int* e_false  = (const int*)d_in[6];
    float* out          = (float*)d_out;

    char* ws = (char*)d_ws;
    // workspace layout (bytes)
    ushort* hT  = (ushort*)(ws);                        //  2,572,288 (128 x 10048 bf16)
    float*  zp  = (float*)(ws + 2572288);               // 40,960,000 (8 x 10000 x 128 f32)
    float*  v   = (float*)(ws + 43532288);              //      1,024
    float*  a   = (float*)(ws + 43533312);              //     40,000
    float*  b   = (float*)(ws + 43573312);              //     40,000
    ushort* zb  = (ushort*)(ws + 43613312);             //  2,560,000
    ushort* zwb = (ushort*)(ws + 46173312);             //  2,560,000
    ushort* WT  = (ushort*)(ws + 48733312);             //    131,072  -> ~48.9 MB

    k_prep<<<64, 256, 0, stream>>>(w, w2, w3, WT, v, hT);
    k_xw<<<dim3(625, 4), 64, 0, stream>>>(x, WT, hT);
    k_adj<<<dim3(79, SPLITS), 256, 0, stream>>>(adj, hT, zp);
    k_node<<<2500, 256, 0, stream>>>(zp, v, w3, a, b, zb, zwb);
    k_edge<<<2048, 256, 0, stream>>>(e_true, e_false, a, b, zb, zwb, out);
}

// Round 9
// 208.083 us; speedup vs baseline: 1.6296x; 1.0033x over previous
//
#include <hip/hip_runtime.h>

// ---------------- problem constants ----------------
#define N_NODES 10000
#define IN_DIM  512
#define OUT_DIM 128
#define NE      262144
#define K_DIM   10000
#define HT_S    10048          // padded hT stride (zeros in [10000,10048))

// ---------------- GEMM2 (adj @ h) tiling ----------------
#define BM 64
#define BN 128
#define BK 64
#define SPLITS 8
#define KSTEPS_TOTAL 157       // ceil(10000/64)
#define STEPS_PER_SPLIT 20     // 7*20 + 17 = 157

typedef __attribute__((ext_vector_type(8))) __bf16 bf16x8;
typedef __attribute__((ext_vector_type(4))) float  f32x4;

__device__ inline ushort f2bf(float f) {
    uint u = __float_as_uint(f);
    return (ushort)((u + 0x7fffu + ((u >> 16) & 1u)) >> 16);
}
__device__ inline float bf2f(ushort s) {
    return __uint_as_float(((uint)s) << 16);
}

// async global -> LDS, 16 bytes per lane (global_load_lds_dwordx4)
__device__ __forceinline__ void gl2lds16(const void* g, void* l) {
    __builtin_amdgcn_global_load_lds(
        (const __attribute__((address_space(1))) void*)g,
        (__attribute__((address_space(3))) void*)l, 16, 0, 0);
}

// ---------------- kernel 0: WT = W^T bf16, v = W2 @ w3[:128], hT pad zero ----
__global__ __launch_bounds__(256) void k_prep(const float* __restrict__ w,
                                              const float* __restrict__ w2,
                                              const float* __restrict__ w3,
                                              ushort* __restrict__ WT,
                                              float* __restrict__ v,
                                              ushort* __restrict__ hT) {
    const int t = threadIdx.x;
    for (int idx = blockIdx.x * 256 + t; idx < IN_DIM * OUT_DIM; idx += gridDim.x * 256) {
        int k = idx >> 7, n = idx & 127;
        WT[n * IN_DIM + k] = f2bf(w[idx]);
    }
    if (blockIdx.x == 0) {
        float s = 0.f;
        for (int j = 0; j < OUT_DIM; ++j) s += w2[t * OUT_DIM + j] * w3[j];
        v[t] = s;
    }
    if (blockIdx.x == 1) {
        for (int idx = t; idx < 128 * (HT_S - N_NODES); idx += 256) {
            int c = idx / (HT_S - N_NODES), r = idx % (HT_S - N_NODES);
            hT[(size_t)c * HT_S + N_NODES + r] = 0;
        }
    }
}

// ---------------- kernel 1: hT = (x @ W)^T bf16 ----------------
// One block per 16 rows; 4 waves split the 128 cols (32 each) -> x read ONCE
// from HBM (20 MB); waves 2-4 hit L1/L2 on the same rows.
__global__ __launch_bounds__(256) void k_xw(const float* __restrict__ x,
                                            const ushort* __restrict__ WT,
                                            ushort* __restrict__ hT) {
    const int tid = threadIdx.x, wave = tid >> 6, lane = tid & 63;
    const int lr = lane & 15, lg = lane >> 4;
    const int r0 = blockIdx.x * 16;       // 625 * 16 = 10000 exactly
    const int c0 = wave * 32;             // 4 waves x 32 cols
    const float* pA = x + (size_t)(r0 + lr) * IN_DIM;

    f32x4 acc[2];
#pragma unroll
    for (int nf = 0; nf < 2; ++nf) acc[nf] = (f32x4){0.f, 0.f, 0.f, 0.f};

#pragma unroll
    for (int st = 0; st < 8; ++st) {
        const int k0 = st * 64;
        bf16x8 abf[2];
#pragma unroll
        for (int kh = 0; kh < 2; ++kh) {
            float4 a0 = *(const float4*)(pA + k0 + kh * 32 + lg * 8);
            float4 a1 = *(const float4*)(pA + k0 + kh * 32 + lg * 8 + 4);
            ushort* ap = (ushort*)&abf[kh];
            ap[0] = f2bf(a0.x); ap[1] = f2bf(a0.y); ap[2] = f2bf(a0.z); ap[3] = f2bf(a0.w);
            ap[4] = f2bf(a1.x); ap[5] = f2bf(a1.y); ap[6] = f2bf(a1.z); ap[7] = f2bf(a1.w);
        }
#pragma unroll
        for (int kh = 0; kh < 2; ++kh)
#pragma unroll
            for (int nf = 0; nf < 2; ++nf) {
                bf16x8 bfv = *(const bf16x8*)(WT + (size_t)(c0 + nf * 16 + lr) * IN_DIM + k0 + kh * 32 + lg * 8);
                acc[nf] = __builtin_amdgcn_mfma_f32_16x16x32_bf16(abf[kh], bfv, acc[nf], 0, 0, 0);
            }
    }

    const int m0 = r0 + lg * 4;           // rows m0..m0+3, 4-aligned, < 10000
#pragma unroll
    for (int nf = 0; nf < 2; ++nf) {
        int c = c0 + nf * 16 + lr;
        ushort4 pk;
        pk.x = f2bf(acc[nf][0]); pk.y = f2bf(acc[nf][1]);
        pk.z = f2bf(acc[nf][2]); pk.w = f2bf(acc[nf][3]);
        *(ushort4*)(hT + (size_t)c * HT_S + m0) = pk;
    }
}

// ---------------- kernel 2: zp[split] = adj @ h ----------------
// BM=64: 16 KB LDS (B only), A direct global->reg, grid 157x8=1256 blocks
// ~4.9/CU resident -> many concurrent A-streams to keep HBM saturated.
__global__ __launch_bounds__(256) void k_adj(const float* __restrict__ adj,
                                             const ushort* __restrict__ hT,
                                             float* __restrict__ zp) {
    __shared__ ushort Bs[BN * BK];        // 16 KB

    const int tid = threadIdx.x, wave = tid >> 6, lane = tid & 63;
    const int lr = lane & 15, lg = lane >> 4;
    const int m0 = blockIdx.x * BM;
    const int split = blockIdx.y;
    const int step0 = split * STEPS_PER_SPLIT;
    const int step1 = min(step0 + STEPS_PER_SPLIT, KSTEPS_TOTAL);

    // B staging descriptors (loop-invariant), both-sides XOR swizzle
    long  bbase[4];
    char* bldst[4];
#pragma unroll
    for (int q = 0; q < 4; ++q) {
        int c = tid + q * 256;
        int row = c >> 3, ch = c & 7;
        bbase[q] = (long)row * HT_S + (long)((ch ^ (row & 7)) * 8);
        bldst[q] = (char*)Bs + c * 16;
    }

    // A row pointer (clamped; out-of-range rows' outputs are discarded)
    const int arow = min(m0 + wave * 16 + lr, N_NODES - 1);
    const float* pA = adj + (size_t)arow * K_DIM;

    f32x4 acc[8];
#pragma unroll
    for (int nf = 0; nf < 8; ++nf) acc[nf] = (f32x4){0.f, 0.f, 0.f, 0.f};

    const char* Bb = (const char*)Bs;

    for (int st = step0; st < step1; ++st) {
        const int k0 = st * BK;

        // stage B via async DMA (16 KB / block / step, hT is L2-resident)
#pragma unroll
        for (int q = 0; q < 4; ++q)
            gl2lds16(hT + (bbase[q] + k0), bldst[q]);

        // A direct to registers: 4 independent dwordx4 (clamped so k-overrun
        // lanes read in-bounds; their products hit B=0 pad rows)
        float4 fa[2][2];
#pragma unroll
        for (int kh = 0; kh < 2; ++kh) {
            int kk = k0 + kh * 32 + lg * 8;
            int kc = (kk <= K_DIM - 8) ? kk : (K_DIM - 8);
            fa[kh][0] = *(const float4*)(pA + kc);
            fa[kh][1] = *(const float4*)(pA + kc + 4);
        }

        __syncthreads();   // B tile visible (vmcnt0 also covers A regs)

        bf16x8 abf[2];
#pragma unroll
        for (int kh = 0; kh < 2; ++kh) {
            ushort* ap = (ushort*)&abf[kh];
            const float* f0 = (const float*)&fa[kh][0];
#pragma unroll
            for (int e = 0; e < 8; ++e) ap[e] = f2bf(f0[e]);
        }

#pragma unroll
        for (int kh = 0; kh < 2; ++kh)
#pragma unroll
            for (int nf = 0; nf < 8; ++nf) {
                int brow = nf * 16 + lr;
                bf16x8 bv = *(const bf16x8*)(Bb + brow * 128 + ((kh * 64 + lg * 16) ^ ((brow & 7) << 4)));
                acc[nf] = __builtin_amdgcn_mfma_f32_16x16x32_bf16(abf[kh], bv, acc[nf], 0, 0, 0);
            }

        __syncthreads();   // all B reads done before next-step overwrite
    }

    // epilogue: write split-partial z
    float* out = zp + (size_t)split * N_NODES * OUT_DIM;
    const int orow = m0 + wave * 16 + lg * 4;
#pragma unroll
    for (int nf = 0; nf < 8; ++nf)
#pragma unroll
        for (int r = 0; r < 4; ++r) {
            int row = orow + r;
            if (row < N_NODES)
                out[(size_t)row * OUT_DIM + nf * 16 + lr] = acc[nf][r];
        }
}

// ---------------- kernel 3: reduce splits + per-node precompute --------------
// Single bf16 z-table (2.5 MB -> fits every XCD's 4 MB L2). No zwb.
__global__ __launch_bounds__(256) void k_node(const float* __restrict__ zp,
                                              const float* __restrict__ v,
                                              float* __restrict__ a,
                                              float* __restrict__ b,
                                              ushort* __restrict__ zb) {
    const int wave = threadIdx.x >> 6, lane = threadIdx.x & 63;
    const int i = blockIdx.x * 4 + wave;
    if (i >= N_NODES) return;
    const int k0 = lane, k1 = lane + 64;

    float z0 = 0.f, z1 = 0.f;
#pragma unroll
    for (int s = 0; s < SPLITS; ++s) {
        const float* row = zp + ((size_t)s * N_NODES + i) * OUT_DIM;
        z0 += row[k0];
        z1 += row[k1];
    }
    zb[(size_t)i * OUT_DIM + k0] = f2bf(z0);
    zb[(size_t)i * OUT_DIM + k1] = f2bf(z1);

    float ra = fmaxf(z0, 0.f) * v[k0] + fmaxf(z1, 0.f) * v[k1];
    float rb = fmaxf(z0, 0.f) * v[OUT_DIM + k0] + fmaxf(z1, 0.f) * v[OUT_DIM + k1];
#pragma unroll
    for (int off = 32; off; off >>= 1) {
        ra += __shfl_down(ra, off);
        rb += __shfl_down(rb, off);
    }
    if (lane == 0) { a[i] = ra; b[i] = rb; }
}

// ---------------- kernel 4: per-edge logit + sigmoid -------------------------
// Single-table gathers (both from zb, L2-resident); w3b held in per-lane regs:
// d = sum_k (z_ik * w3b_k) * z_jk.  2 edges/wave via 32-lane halves.
__global__ __launch_bounds__(256) void k_edge(const int* __restrict__ e_true,
                                              const int* __restrict__ e_false,
                                              const float* __restrict__ a,
                                              const float* __restrict__ b,
                                              const ushort* __restrict__ zb,
                                              const float* __restrict__ w3,
                                              float* __restrict__ out) {
    const int lane = threadIdx.x & 63;
    const int half = lane >> 5, l32 = lane & 31;
    const int gw   = (blockIdx.x * blockDim.x + threadIdx.x) >> 6;
    const int nw   = (gridDim.x * blockDim.x) >> 6;

    // lane l32 owns k = 4*l32 .. 4*l32+3
    const float4 wv = *(const float4*)(w3 + OUT_DIM + l32 * 4);

    for (int e = gw * 2 + half; e < 2 * NE; e += nw * 2) {
        int2 ij = (e < NE) ? ((const int2*)e_true)[e] : ((const int2*)e_false)[e - NE];
        int i = ij.x, j = ij.y;

        uint2 zi = *(const uint2*)(zb + (size_t)i * OUT_DIM + l32 * 4);
        uint2 zj = *(const uint2*)(zb + (size_t)j * OUT_DIM + l32 * 4);
        float d = wv.x * bf2f((ushort)(zi.x & 0xffffu)) * bf2f((ushort)(zj.x & 0xffffu))
                + wv.y * bf2f((ushort)(zi.x >> 16))     * bf2f((ushort)(zj.x >> 16))
                + wv.z * bf2f((ushort)(zi.y & 0xffffu)) * bf2f((ushort)(zj.y & 0xffffu))
                + wv.w * bf2f((ushort)(zi.y >> 16))     * bf2f((ushort)(zj.y >> 16));
#pragma unroll
        for (int off = 16; off; off >>= 1) d += __shfl_xor(d, off, 32);
        if (l32 == 0) {
            float logit = a[i] + b[j] + d;
            out[e] = 1.0f / (1.0f + __expf(-logit));
        }
    }
}

// ---------------- launch ----------------
extern "C" void kernel_launch(void* const* d_in, const int* in_sizes, int n_in,
                              void* d_out, int out_size, void* d_ws, size_t ws_size,
                              hipStream_t stream) {
    const float* x      = (const float*)d_in[0];
    const float* adj    = (const float*)d_in[1];
    const float* w      = (const float*)d_in[2];
    const float* w2     = (const float*)d_in[3];
    const float* w3     = (const float*)d_in[4];
    const int* e_true   = (const int*)d_in[5];
    const int* e_false  = (const int*)d_in[6];
    float* out          = (float*)d_out;

    char* ws = (char*)d_ws;
    // workspace layout (bytes)
    ushort* hT  = (ushort*)(ws);                        //  2,572,288 (128 x 10048 bf16)
    float*  zp  = (float*)(ws + 2572288);               // 40,960,000 (8 x 10000 x 128 f32)
    float*  v   = (float*)(ws + 43532288);              //      1,024
    float*  a   = (float*)(ws + 43533312);              //     40,000
    float*  b   = (float*)(ws + 43573312);              //     40,000
    ushort* zb  = (ushort*)(ws + 43613312);             //  2,560,000
    ushort* WT  = (ushort*)(ws + 46173312);             //    131,072  -> ~46.3 MB

    k_prep<<<64, 256, 0, stream>>>(w, w2, w3, WT, v, hT);
    k_xw<<<625, 256, 0, stream>>>(x, WT, hT);
    k_adj<<<dim3(157, SPLITS), 256, 0, stream>>>(adj, hT, zp);
    k_node<<<2500, 256, 0, stream>>>(zp, v, a, b, zb);
    k_edge<<<2048, 256, 0, stream>>>(e_true, e_false, a, b, zb, w3, out);
}